// Round 3
// baseline (229.253 us; speedup 1.0000x reference)
//
#include <hip/hip_runtime.h>
#include <hip/hip_bf16.h>

typedef __attribute__((ext_vector_type(8))) short bf16x8;
typedef __attribute__((ext_vector_type(16))) float f32x16;

#define BNSCL 0.9999950000375f   /* 1/sqrt(1+1e-5) */

// ---------------------------------------------------------------------------
// Kernel 1: per-point scores MLP + softmax (weights in LDS, 2 pts/thread).
// Fused tail: blocks < 256 also transpose weight_bank -> wbT bf16 [o][cm].
// ---------------------------------------------------------------------------
__global__ __launch_bounds__(256) void k_scores(
    const float* __restrict__ xyz,
    const float* __restrict__ w1, const float* __restrict__ g1, const float* __restrict__ be1,
    const float* __restrict__ w2, const float* __restrict__ g2, const float* __restrict__ be2,
    const float* __restrict__ w3, const float* __restrict__ g3, const float* __restrict__ be3,
    const float* __restrict__ w4, const float* __restrict__ b4,
    const float* __restrict__ wb, __hip_bfloat16* __restrict__ wbt,
    float* __restrict__ scores)
{
    __shared__ float lw[856];
    const int tid = threadIdx.x;

    // fused weight-bank transpose (one elem per thread, first 256 blocks)
    if (blockIdx.x < 256) {
        int idx = blockIdx.x * 256 + tid;       // 0..65535
        int o = idx >> 10, cm = idx & 1023;
        wbt[idx] = __float2bfloat16(wb[cm * 64 + o]);
    }

    if (tid < 112) lw[tid] = w1[tid];
    lw[112 + tid] = w2[tid];
    lw[368 + tid] = w3[tid];
    if (tid < 128) lw[624 + tid] = w4[tid];
    if (tid < 8)   lw[752 + tid] = b4[tid];
    if (tid < 16) {
        lw[760 + tid] = g1[tid] * BNSCL;  lw[776 + tid] = be1[tid];
        lw[792 + tid] = g2[tid] * BNSCL;  lw[808 + tid] = be2[tid];
        lw[824 + tid] = g3[tid] * BNSCL;  lw[840 + tid] = be3[tid];
    }
    __syncthreads();

    float in7[2][7], h1[2][16], h2[2][16], s[2][8];

#pragma unroll
    for (int q = 0; q < 2; ++q) {
        int g = blockIdx.x * 512 + q * 256 + tid;
        int b = g >> 15;
        int p = g & 32767;
        int pc = p & ~31;
        const float* xb = xyz + (size_t)b * 98304;
        float cx = xb[pc], cy = xb[32768 + pc], cz = xb[65536 + pc];
        float dx = xb[p] - cx, dy = xb[32768 + p] - cy, dz = xb[65536 + p] - cz;
        in7[q][0] = cx; in7[q][1] = cy; in7[q][2] = cz;
        in7[q][3] = dx; in7[q][4] = dy; in7[q][5] = dz;
        in7[q][6] = sqrtf(dx * dx + dy * dy + dz * dz);
    }

#pragma unroll
    for (int o = 0; o < 16; ++o) {
        float a0 = 0.f, a1 = 0.f;
#pragma unroll
        for (int c = 0; c < 7; ++c) {
            float w = lw[o * 7 + c];
            a0 += w * in7[0][c]; a1 += w * in7[1][c];
        }
        float gs = lw[760 + o], bb = lw[776 + o];
        h1[0][o] = fmaxf(a0 * gs + bb, 0.f);
        h1[1][o] = fmaxf(a1 * gs + bb, 0.f);
    }
#pragma unroll
    for (int o = 0; o < 16; ++o) {
        float a0 = 0.f, a1 = 0.f;
#pragma unroll
        for (int c = 0; c < 16; ++c) {
            float w = lw[112 + o * 16 + c];
            a0 += w * h1[0][c]; a1 += w * h1[1][c];
        }
        float gs = lw[792 + o], bb = lw[808 + o];
        h2[0][o] = fmaxf(a0 * gs + bb, 0.f);
        h2[1][o] = fmaxf(a1 * gs + bb, 0.f);
    }
#pragma unroll
    for (int o = 0; o < 16; ++o) {
        float a0 = 0.f, a1 = 0.f;
#pragma unroll
        for (int c = 0; c < 16; ++c) {
            float w = lw[368 + o * 16 + c];
            a0 += w * h2[0][c]; a1 += w * h2[1][c];
        }
        float gs = lw[824 + o], bb = lw[840 + o];
        h1[0][o] = fmaxf(a0 * gs + bb, 0.f);
        h1[1][o] = fmaxf(a1 * gs + bb, 0.f);
    }
#pragma unroll
    for (int o = 0; o < 8; ++o) {
        float bb = lw[752 + o];
        float a0 = bb, a1 = bb;
#pragma unroll
        for (int c = 0; c < 16; ++c) {
            float w = lw[624 + o * 16 + c];
            a0 += w * h1[0][c]; a1 += w * h1[1][c];
        }
        s[0][o] = a0; s[1][o] = a1;
    }

#pragma unroll
    for (int q = 0; q < 2; ++q) {
        int g = blockIdx.x * 512 + q * 256 + tid;
        float mx = s[q][0];
#pragma unroll
        for (int i = 1; i < 8; ++i) mx = fmaxf(mx, s[q][i]);
        float sum = 0.f;
#pragma unroll
        for (int i = 0; i < 8; ++i) { s[q][i] = __expf(s[q][i] - mx); sum += s[q][i]; }
        float inv = 1.f / sum;
        float4 lo = {s[q][0] * inv, s[q][1] * inv, s[q][2] * inv, s[q][3] * inv};
        float4 hi = {s[q][4] * inv, s[q][5] * inv, s[q][6] * inv, s[q][7] * inv};
        *(float4*)(scores + (size_t)g * 8) = lo;
        *(float4*)(scores + (size_t)g * 8 + 4) = hi;
    }
}

// ---------------------------------------------------------------------------
// Kernel 2: main einsum via 32x32x16 MFMA, 2 point-tiles x 2 o-tiles / wave.
// Block = 256 thr (4 waves) = 256 points. LDS = 64o x 256cm bf16 = 32 KB
// (XOR-swizzled 16B chunks), 4 phases, 4 blocks/CU.
// Per kk-step/wave: 2 ds_read_b128 (A, shared by both pt) + 4 MFMA.
// ---------------------------------------------------------------------------
__global__ __launch_bounds__(256, 4) void k_main(
    const float* __restrict__ feat,
    const float* __restrict__ scores,
    const __hip_bfloat16* __restrict__ wbt,
    const float* __restrict__ bn_g, const float* __restrict__ bn_b,
    float* __restrict__ out)
{
    __shared__ __align__(16) short lwb[64 * 256];   // 32 KB

    const int tid  = threadIdx.x;
    const int lane = tid & 63;
    const int wave = tid >> 6;          // 0..3
    const int l31  = lane & 31;         // point within tile / A-B row-col
    const int lh   = lane >> 5;         // 0..1 (k-half)

    const int pblock = blockIdx.x * 256;
    const int b    = pblock >> 15;
    const int pl0  = pblock & 32767;            // within-batch base point

    const int ptl0 = pl0 + (wave * 2 + 0) * 32; // point-tile q=0 (group-aligned)
    const int ptl1 = pl0 + (wave * 2 + 1) * 32; // point-tile q=1
    const int pc0  = ptl0 + l31;
    const int pc1  = ptl1 + l31;

    const float* fb = feat + (size_t)b * 2097152;   // (64, 32768)

    // scores for this lane's two points
    const float* sp0 = scores + ((size_t)(pblock + (wave * 2) * 32 + l31)) * 8;
    const float* sp1 = sp0 + 256;               // next tile = +32 pts * 8
    float4 s0lo = *(const float4*)sp0, s0hi = *(const float4*)(sp0 + 4);
    float4 s1lo = *(const float4*)sp1, s1hi = *(const float4*)(sp1 + 4);

    f32x16 acc[2][2];
#pragma unroll
    for (int q = 0; q < 2; ++q)
#pragma unroll
        for (int ot = 0; ot < 2; ++ot) {
            f32x16 z = {0.f,0.f,0.f,0.f,0.f,0.f,0.f,0.f,0.f,0.f,0.f,0.f,0.f,0.f,0.f,0.f};
            acc[q][ot] = z;
        }

    const ushort* wsrc = (const ushort*)wbt;

#pragma unroll
    for (int phase = 0; phase < 4; ++phase) {
        // ---- stage wbT[:, phase*256 .. +256) into LDS, swizzled ----
#pragma unroll
        for (int it = 0; it < 8; ++it) {
            int chunk = it * 256 + tid;          // 0..2047
            int o = chunk >> 5, c8 = chunk & 31; // 32 chunks of 8 cm per o-row
            int4 v = *(const int4*)(wsrc + (o << 10) + (phase << 8) + (c8 << 3));
            *(int4*)&lwb[(o << 8) + (((c8 ^ (o & 31)) & 31) << 3)] = v;
        }
        __syncthreads();

#pragma unroll 4
        for (int kk = 0; kk < 16; ++kk) {
            // this lane's channel: c' = phase*32 + kk*2 + lh; feat row:
            int cr = ((phase & 1) << 5) + kk * 2 + lh;     // 0..63
            const float* fr = fb + ((size_t)cr << 15);
            float fv0, fv1;
            if (phase < 2) {                                // diff half
                fv0 = fr[pc0] - fr[ptl0];
                fv1 = fr[pc1] - fr[ptl1];
            } else {                                        // raw half
                fv0 = fr[pc0];
                fv1 = fr[pc1];
            }

            int4 bi0, bi1;
            { __hip_bfloat162 t = __float22bfloat162_rn(make_float2(fv0*s0lo.x, fv0*s0lo.y)); __builtin_memcpy(&bi0.x, &t, 4); }
            { __hip_bfloat162 t = __float22bfloat162_rn(make_float2(fv0*s0lo.z, fv0*s0lo.w)); __builtin_memcpy(&bi0.y, &t, 4); }
            { __hip_bfloat162 t = __float22bfloat162_rn(make_float2(fv0*s0hi.x, fv0*s0hi.y)); __builtin_memcpy(&bi0.z, &t, 4); }
            { __hip_bfloat162 t = __float22bfloat162_rn(make_float2(fv0*s0hi.z, fv0*s0hi.w)); __builtin_memcpy(&bi0.w, &t, 4); }
            { __hip_bfloat162 t = __float22bfloat162_rn(make_float2(fv1*s1lo.x, fv1*s1lo.y)); __builtin_memcpy(&bi1.x, &t, 4); }
            { __hip_bfloat162 t = __float22bfloat162_rn(make_float2(fv1*s1lo.z, fv1*s1lo.w)); __builtin_memcpy(&bi1.y, &t, 4); }
            { __hip_bfloat162 t = __float22bfloat162_rn(make_float2(fv1*s1hi.x, fv1*s1hi.y)); __builtin_memcpy(&bi1.z, &t, 4); }
            { __hip_bfloat162 t = __float22bfloat162_rn(make_float2(fv1*s1hi.z, fv1*s1hi.w)); __builtin_memcpy(&bi1.w, &t, 4); }
            bf16x8 bv0 = __builtin_bit_cast(bf16x8, bi0);
            bf16x8 bv1 = __builtin_bit_cast(bf16x8, bi1);

            int swz = ((kk * 2 + lh) ^ l31) & 31;
#pragma unroll
            for (int ot = 0; ot < 2; ++ot) {
                int o = ot * 32 + l31;
                bf16x8 af = *(const bf16x8*)&lwb[(o << 8) + (swz << 3)];
                acc[0][ot] = __builtin_amdgcn_mfma_f32_32x32x16_bf16(af, bv0, acc[0][ot], 0, 0, 0);
                acc[1][ot] = __builtin_amdgcn_mfma_f32_32x32x16_bf16(af, bv1, acc[1][ot], 0, 0, 0);
            }
        }
        __syncthreads();
    }

    // ---------------- epilogue: BN + ReLU + coalesced store ------------------
#pragma unroll
    for (int q = 0; q < 2; ++q) {
        int pcol = (q == 0) ? pc0 : pc1;
#pragma unroll
        for (int ot = 0; ot < 2; ++ot) {
#pragma unroll
            for (int r = 0; r < 16; ++r) {
                int o = ot * 32 + (r & 3) + ((r >> 2) << 3) + (lh << 2);
                float v = acc[q][ot][r];
                v = v * (bn_g[o] * BNSCL) + bn_b[o];
                v = fmaxf(v, 0.f);
                out[((size_t)(b * 64 + o) << 15) + pcol] = v;
            }
        }
    }
}

// ---------------------------------------------------------------------------
extern "C" void kernel_launch(void* const* d_in, const int* in_sizes, int n_in,
                              void* d_out, int out_size, void* d_ws, size_t ws_size,
                              hipStream_t stream)
{
    const float* features = (const float*)d_in[0];
    const float* xyz      = (const float*)d_in[1];
    const float* w1  = (const float*)d_in[2];
    const float* g1  = (const float*)d_in[3];
    const float* be1 = (const float*)d_in[4];
    const float* w2  = (const float*)d_in[5];
    const float* g2  = (const float*)d_in[6];
    const float* be2 = (const float*)d_in[7];
    const float* w3  = (const float*)d_in[8];
    const float* g3  = (const float*)d_in[9];
    const float* be3 = (const float*)d_in[10];
    const float* w4  = (const float*)d_in[11];
    const float* b4  = (const float*)d_in[12];
    const float* wb  = (const float*)d_in[13];
    const float* bn_g = (const float*)d_in[14];
    const float* bn_b = (const float*)d_in[15];

    float* scores = (float*)d_ws;                                   // 8 MB
    __hip_bfloat16* wbt = (__hip_bfloat16*)((char*)d_ws + 8388608); // 128 KB

    k_scores<<<512, 256, 0, stream>>>(xyz, w1, g1, be1, w2, g2, be2,
                                      w3, g3, be3, w4, b4, wb, wbt, scores);
    k_main<<<1024, 256, 0, stream>>>(features, scores, wbt, bn_g, bn_b,
                                     (float*)d_out);
}

// Round 4
// 188.954 us; speedup vs baseline: 1.2133x; 1.2133x over previous
//
#include <hip/hip_runtime.h>
#include <hip/hip_bf16.h>

typedef _Float16 f16;
typedef __attribute__((ext_vector_type(2))) _Float16 f16x2;
typedef __attribute__((ext_vector_type(8))) _Float16 f16x8;
typedef __attribute__((ext_vector_type(16))) float f32x16;

#define BNSCL 0.9999950000375f   /* 1/sqrt(1+1e-5) */

// ---------------------------------------------------------------------------
// Kernel 1: per-point scores MLP + softmax (weights in LDS, 2 pts/thread),
// output f16x8 per point. Fused: blocks < 256 also build wbtA = weight bank
// in MFMA A-fragment order, f16:
//   wbtA[(((ot*64 + ks)*64 + lane)*8 + j] = wb[c'][m=j][o]
//   with c' = ks*2 + (lane>>5), o = ot*32 + (lane&31).
// ---------------------------------------------------------------------------
__global__ __launch_bounds__(256) void k_scores(
    const float* __restrict__ xyz,
    const float* __restrict__ w1, const float* __restrict__ g1, const float* __restrict__ be1,
    const float* __restrict__ w2, const float* __restrict__ g2, const float* __restrict__ be2,
    const float* __restrict__ w3, const float* __restrict__ g3, const float* __restrict__ be3,
    const float* __restrict__ w4, const float* __restrict__ b4,
    const float* __restrict__ wb, f16* __restrict__ wbtA,
    f16* __restrict__ scores)
{
    __shared__ float lw[856];
    const int tid = threadIdx.x;

    // fused weight-bank fragment-order transpose (1 elem/thread, blocks 0-255)
    if (blockIdx.x < 256) {
        int idx = blockIdx.x * 256 + tid;       // 0..65535
        int j    = idx & 7;
        int lane = (idx >> 3) & 63;
        int ks   = (idx >> 9) & 63;
        int ot   = idx >> 15;
        int cp   = ks * 2 + (lane >> 5);        // 0..127
        int o    = ot * 32 + (lane & 31);
        wbtA[idx] = (f16)wb[(cp * 8 + j) * 64 + o];
    }

    if (tid < 112) lw[tid] = w1[tid];
    lw[112 + tid] = w2[tid];
    lw[368 + tid] = w3[tid];
    if (tid < 128) lw[624 + tid] = w4[tid];
    if (tid < 8)   lw[752 + tid] = b4[tid];
    if (tid < 16) {
        lw[760 + tid] = g1[tid] * BNSCL;  lw[776 + tid] = be1[tid];
        lw[792 + tid] = g2[tid] * BNSCL;  lw[808 + tid] = be2[tid];
        lw[824 + tid] = g3[tid] * BNSCL;  lw[840 + tid] = be3[tid];
    }
    __syncthreads();

    float in7[2][7], h1[2][16], h2[2][16], s[2][8];

#pragma unroll
    for (int q = 0; q < 2; ++q) {
        int g = blockIdx.x * 512 + q * 256 + tid;
        int b = g >> 15;
        int p = g & 32767;
        int pc = p & ~31;
        const float* xb = xyz + (size_t)b * 98304;
        float cx = xb[pc], cy = xb[32768 + pc], cz = xb[65536 + pc];
        float dx = xb[p] - cx, dy = xb[32768 + p] - cy, dz = xb[65536 + p] - cz;
        in7[q][0] = cx; in7[q][1] = cy; in7[q][2] = cz;
        in7[q][3] = dx; in7[q][4] = dy; in7[q][5] = dz;
        in7[q][6] = sqrtf(dx * dx + dy * dy + dz * dz);
    }

#pragma unroll
    for (int o = 0; o < 16; ++o) {
        float a0 = 0.f, a1 = 0.f;
#pragma unroll
        for (int c = 0; c < 7; ++c) {
            float w = lw[o * 7 + c];
            a0 += w * in7[0][c]; a1 += w * in7[1][c];
        }
        float gs = lw[760 + o], bb = lw[776 + o];
        h1[0][o] = fmaxf(a0 * gs + bb, 0.f);
        h1[1][o] = fmaxf(a1 * gs + bb, 0.f);
    }
#pragma unroll
    for (int o = 0; o < 16; ++o) {
        float a0 = 0.f, a1 = 0.f;
#pragma unroll
        for (int c = 0; c < 16; ++c) {
            float w = lw[112 + o * 16 + c];
            a0 += w * h1[0][c]; a1 += w * h1[1][c];
        }
        float gs = lw[792 + o], bb = lw[808 + o];
        h2[0][o] = fmaxf(a0 * gs + bb, 0.f);
        h2[1][o] = fmaxf(a1 * gs + bb, 0.f);
    }
#pragma unroll
    for (int o = 0; o < 16; ++o) {
        float a0 = 0.f, a1 = 0.f;
#pragma unroll
        for (int c = 0; c < 16; ++c) {
            float w = lw[368 + o * 16 + c];
            a0 += w * h2[0][c]; a1 += w * h2[1][c];
        }
        float gs = lw[824 + o], bb = lw[840 + o];
        h1[0][o] = fmaxf(a0 * gs + bb, 0.f);
        h1[1][o] = fmaxf(a1 * gs + bb, 0.f);
    }
#pragma unroll
    for (int o = 0; o < 8; ++o) {
        float bb = lw[752 + o];
        float a0 = bb, a1 = bb;
#pragma unroll
        for (int c = 0; c < 16; ++c) {
            float w = lw[624 + o * 16 + c];
            a0 += w * h1[0][c]; a1 += w * h1[1][c];
        }
        s[0][o] = a0; s[1][o] = a1;
    }

#pragma unroll
    for (int q = 0; q < 2; ++q) {
        int g = blockIdx.x * 512 + q * 256 + tid;
        float mx = s[q][0];
#pragma unroll
        for (int i = 1; i < 8; ++i) mx = fmaxf(mx, s[q][i]);
        float sum = 0.f;
#pragma unroll
        for (int i = 0; i < 8; ++i) { s[q][i] = __expf(s[q][i] - mx); sum += s[q][i]; }
        float inv = 1.f / sum;
        f16x8 o8;
#pragma unroll
        for (int i = 0; i < 8; ++i) o8[i] = (f16)(s[q][i] * inv);
        *(f16x8*)(scores + (size_t)g * 8) = o8;
    }
}

// ---------------------------------------------------------------------------
// Kernel 2: main einsum, 32x32x16 f16 MFMA. NO LDS, NO barriers.
// Wave = 64 points (2 point-tiles) x all 64 outputs (2 o-tiles).
// A-frags loaded coalesced from fragment-ordered wbtA (hot 128 KB in L1/L2).
// diff (ks=kk) and raw (ks=kk+32) paired -> each feat row read ONCE.
// ---------------------------------------------------------------------------
__global__ __launch_bounds__(256, 3) void k_main(
    const float* __restrict__ feat,
    const f16* __restrict__ scores,
    const f16* __restrict__ wbtA,
    const float* __restrict__ bn_g, const float* __restrict__ bn_b,
    float* __restrict__ out)
{
    const int tid  = threadIdx.x;
    const int lane = tid & 63;
    const int wave = tid >> 6;          // 0..3
    const int l31  = lane & 31;
    const int lh   = lane >> 5;         // 0..1

    const int pblock = blockIdx.x * 256;        // global point base
    const int b    = pblock >> 15;
    const int pt0  = (pblock & 32767) + wave * 64;   // within-batch, 32-aligned
    const int pc0  = pt0 + l31;
    const int pc1  = pc0 + 32;

    const float* fb = feat + (size_t)b * 2097152;    // (64, 32768)

    // scores (f16) for this lane's two points
    const int gpt = pblock + wave * 64 + l31;
    f16x8 sv0 = *(const f16x8*)(scores + (size_t)gpt * 8);
    f16x8 sv1 = *(const f16x8*)(scores + (size_t)(gpt + 32) * 8);
    const f16x2 s0a = {sv0[0], sv0[1]}, s0b = {sv0[2], sv0[3]},
                s0c = {sv0[4], sv0[5]}, s0d = {sv0[6], sv0[7]};
    const f16x2 s1a = {sv1[0], sv1[1]}, s1b = {sv1[2], sv1[3]},
                s1c = {sv1[4], sv1[5]}, s1d = {sv1[6], sv1[7]};

    f32x16 acc00 = {}, acc01 = {}, acc10 = {}, acc11 = {};

    const f16* A = wbtA + (lane << 3);           // lane's slot in each 1KB frag

#pragma unroll 2
    for (int kk = 0; kk < 32; ++kk) {
        const float* fr = fb + ((size_t)(kk * 2 + lh) << 15);

        // A-frags: ot in {0,1}, ks in {kk (diff), kk+32 (raw)}
        f16x8 aD0 = *(const f16x8*)(A + ((size_t)(0 * 64 + kk)       << 9));
        f16x8 aD1 = *(const f16x8*)(A + ((size_t)(1 * 64 + kk)       << 9));
        f16x8 aR0 = *(const f16x8*)(A + ((size_t)(0 * 64 + kk + 32)  << 9));
        f16x8 aR1 = *(const f16x8*)(A + ((size_t)(1 * 64 + kk + 32)  << 9));

        float fv0 = fr[pc0], fv1 = fr[pc1];
        float fc0 = fr[pt0], fc1 = fr[pt0 + 32];

        f16 hR0 = (f16)fv0,          hR1 = (f16)fv1;
        f16 hD0 = (f16)(fv0 - fc0),  hD1 = (f16)(fv1 - fc1);
        f16x2 fR0 = {hR0, hR0}, fR1 = {hR1, hR1};
        f16x2 fD0 = {hD0, hD0}, fD1 = {hD1, hD1};

        f16x2 d0a = fD0 * s0a, d0b = fD0 * s0b, d0c = fD0 * s0c, d0d = fD0 * s0d;
        f16x2 d1a = fD1 * s1a, d1b = fD1 * s1b, d1c = fD1 * s1c, d1d = fD1 * s1d;
        f16x2 r0a = fR0 * s0a, r0b = fR0 * s0b, r0c = fR0 * s0c, r0d = fR0 * s0d;
        f16x2 r1a = fR1 * s1a, r1b = fR1 * s1b, r1c = fR1 * s1c, r1d = fR1 * s1d;

        f16x8 bD0 = {d0a[0],d0a[1],d0b[0],d0b[1],d0c[0],d0c[1],d0d[0],d0d[1]};
        f16x8 bD1 = {d1a[0],d1a[1],d1b[0],d1b[1],d1c[0],d1c[1],d1d[0],d1d[1]};
        f16x8 bR0 = {r0a[0],r0a[1],r0b[0],r0b[1],r0c[0],r0c[1],r0d[0],r0d[1]};
        f16x8 bR1 = {r1a[0],r1a[1],r1b[0],r1b[1],r1c[0],r1c[1],r1d[0],r1d[1]};

        acc00 = __builtin_amdgcn_mfma_f32_32x32x16_f16(aD0, bD0, acc00, 0, 0, 0);
        acc01 = __builtin_amdgcn_mfma_f32_32x32x16_f16(aD1, bD0, acc01, 0, 0, 0);
        acc10 = __builtin_amdgcn_mfma_f32_32x32x16_f16(aD0, bD1, acc10, 0, 0, 0);
        acc11 = __builtin_amdgcn_mfma_f32_32x32x16_f16(aD1, bD1, acc11, 0, 0, 0);
        acc00 = __builtin_amdgcn_mfma_f32_32x32x16_f16(aR0, bR0, acc00, 0, 0, 0);
        acc01 = __builtin_amdgcn_mfma_f32_32x32x16_f16(aR1, bR0, acc01, 0, 0, 0);
        acc10 = __builtin_amdgcn_mfma_f32_32x32x16_f16(aR0, bR1, acc10, 0, 0, 0);
        acc11 = __builtin_amdgcn_mfma_f32_32x32x16_f16(aR1, bR1, acc11, 0, 0, 0);
    }

    // ---------------- epilogue: BN + ReLU + coalesced store ------------------
    // C layout (verified R3): col = lane&31, row = (r&3) + 8*(r>>2) + 4*lh
#pragma unroll
    for (int q = 0; q < 2; ++q) {
        int pcol = (q == 0) ? pc0 : pc1;
#pragma unroll
        for (int ot = 0; ot < 2; ++ot) {
            const f32x16& a = (q == 0) ? (ot == 0 ? acc00 : acc01)
                                       : (ot == 0 ? acc10 : acc11);
#pragma unroll
            for (int r = 0; r < 16; ++r) {
                int o = ot * 32 + (r & 3) + ((r >> 2) << 3) + (lh << 2);
                float v = a[r];
                v = v * (bn_g[o] * BNSCL) + bn_b[o];
                v = fmaxf(v, 0.f);
                out[((size_t)(b * 64 + o) << 15) + pcol] = v;
            }
        }
    }
}

// ---------------------------------------------------------------------------
extern "C" void kernel_launch(void* const* d_in, const int* in_sizes, int n_in,
                              void* d_out, int out_size, void* d_ws, size_t ws_size,
                              hipStream_t stream)
{
    const float* features = (const float*)d_in[0];
    const float* xyz      = (const float*)d_in[1];
    const float* w1  = (const float*)d_in[2];
    const float* g1  = (const float*)d_in[3];
    const float* be1 = (const float*)d_in[4];
    const float* w2  = (const float*)d_in[5];
    const float* g2  = (const float*)d_in[6];
    const float* be2 = (const float*)d_in[7];
    const float* w3  = (const float*)d_in[8];
    const float* g3  = (const float*)d_in[9];
    const float* be3 = (const float*)d_in[10];
    const float* w4  = (const float*)d_in[11];
    const float* b4  = (const float*)d_in[12];
    const float* wb  = (const float*)d_in[13];
    const float* bn_g = (const float*)d_in[14];
    const float* bn_b = (const float*)d_in[15];

    f16* scores = (f16*)d_ws;                             // 4 MB (262144 x 16B)
    f16* wbtA   = (f16*)((char*)d_ws + (4u << 20));       // 128 KB

    k_scores<<<512, 256, 0, stream>>>(xyz, w1, g1, be1, w2, g2, be2,
                                      w3, g3, be3, w4, b4, wb, wbtA, scores);
    k_main<<<1024, 256, 0, stream>>>(features, scores, wbtA, bn_g, bn_b,
                                     (float*)d_out);
}

// Round 5
// 180.318 us; speedup vs baseline: 1.2714x; 1.0479x over previous
//
#include <hip/hip_runtime.h>
#include <hip/hip_bf16.h>

typedef _Float16 f16;
typedef __attribute__((ext_vector_type(2))) _Float16 f16x2;
typedef __attribute__((ext_vector_type(8))) _Float16 f16x8;
typedef __attribute__((ext_vector_type(16))) float f32x16;

#define BNSCL 0.9999950000375f   /* 1/sqrt(1+1e-5) */

// ---------------------------------------------------------------------------
// Kernel 1: per-point scores MLP + softmax (weights in LDS, 2 pts/thread),
// output f16x8 per point. Fused: blocks < 256 also build wbtA = weight bank
// in MFMA A-fragment order, f16:
//   wbtA[((ot*64 + ks)*64 + lane)*8 + j] = wb[c'][m=j][o]
//   with c' = ks*2 + (lane>>5), o = ot*32 + (lane&31).
// ---------------------------------------------------------------------------
__global__ __launch_bounds__(256) void k_scores(
    const float* __restrict__ xyz,
    const float* __restrict__ w1, const float* __restrict__ g1, const float* __restrict__ be1,
    const float* __restrict__ w2, const float* __restrict__ g2, const float* __restrict__ be2,
    const float* __restrict__ w3, const float* __restrict__ g3, const float* __restrict__ be3,
    const float* __restrict__ w4, const float* __restrict__ b4,
    const float* __restrict__ wb, f16* __restrict__ wbtA,
    f16* __restrict__ scores)
{
    __shared__ float lw[856];
    const int tid = threadIdx.x;

    // fused weight-bank fragment-order transpose (1 elem/thread, blocks 0-255)
    if (blockIdx.x < 256) {
        int idx = blockIdx.x * 256 + tid;       // 0..65535
        int j    = idx & 7;
        int lane = (idx >> 3) & 63;
        int ks   = (idx >> 9) & 63;
        int ot   = idx >> 15;
        int cp   = ks * 2 + (lane >> 5);        // 0..127
        int o    = ot * 32 + (lane & 31);
        wbtA[idx] = (f16)wb[(cp * 8 + j) * 64 + o];
    }

    if (tid < 112) lw[tid] = w1[tid];
    lw[112 + tid] = w2[tid];
    lw[368 + tid] = w3[tid];
    if (tid < 128) lw[624 + tid] = w4[tid];
    if (tid < 8)   lw[752 + tid] = b4[tid];
    if (tid < 16) {
        lw[760 + tid] = g1[tid] * BNSCL;  lw[776 + tid] = be1[tid];
        lw[792 + tid] = g2[tid] * BNSCL;  lw[808 + tid] = be2[tid];
        lw[824 + tid] = g3[tid] * BNSCL;  lw[840 + tid] = be3[tid];
    }
    __syncthreads();

    float in7[2][7], h1[2][16], h2[2][16], s[2][8];

#pragma unroll
    for (int q = 0; q < 2; ++q) {
        int g = blockIdx.x * 512 + q * 256 + tid;
        int b = g >> 15;
        int p = g & 32767;
        int pc = p & ~31;
        const float* xb = xyz + (size_t)b * 98304;
        float cx = xb[pc], cy = xb[32768 + pc], cz = xb[65536 + pc];
        float dx = xb[p] - cx, dy = xb[32768 + p] - cy, dz = xb[65536 + p] - cz;
        in7[q][0] = cx; in7[q][1] = cy; in7[q][2] = cz;
        in7[q][3] = dx; in7[q][4] = dy; in7[q][5] = dz;
        in7[q][6] = sqrtf(dx * dx + dy * dy + dz * dz);
    }

#pragma unroll
    for (int o = 0; o < 16; ++o) {
        float a0 = 0.f, a1 = 0.f;
#pragma unroll
        for (int c = 0; c < 7; ++c) {
            float w = lw[o * 7 + c];
            a0 += w * in7[0][c]; a1 += w * in7[1][c];
        }
        float gs = lw[760 + o], bb = lw[776 + o];
        h1[0][o] = fmaxf(a0 * gs + bb, 0.f);
        h1[1][o] = fmaxf(a1 * gs + bb, 0.f);
    }
#pragma unroll
    for (int o = 0; o < 16; ++o) {
        float a0 = 0.f, a1 = 0.f;
#pragma unroll
        for (int c = 0; c < 16; ++c) {
            float w = lw[112 + o * 16 + c];
            a0 += w * h1[0][c]; a1 += w * h1[1][c];
        }
        float gs = lw[792 + o], bb = lw[808 + o];
        h2[0][o] = fmaxf(a0 * gs + bb, 0.f);
        h2[1][o] = fmaxf(a1 * gs + bb, 0.f);
    }
#pragma unroll
    for (int o = 0; o < 16; ++o) {
        float a0 = 0.f, a1 = 0.f;
#pragma unroll
        for (int c = 0; c < 16; ++c) {
            float w = lw[368 + o * 16 + c];
            a0 += w * h2[0][c]; a1 += w * h2[1][c];
        }
        float gs = lw[824 + o], bb = lw[840 + o];
        h1[0][o] = fmaxf(a0 * gs + bb, 0.f);
        h1[1][o] = fmaxf(a1 * gs + bb, 0.f);
    }
#pragma unroll
    for (int o = 0; o < 8; ++o) {
        float bb = lw[752 + o];
        float a0 = bb, a1 = bb;
#pragma unroll
        for (int c = 0; c < 16; ++c) {
            float w = lw[624 + o * 16 + c];
            a0 += w * h1[0][c]; a1 += w * h1[1][c];
        }
        s[0][o] = a0; s[1][o] = a1;
    }

#pragma unroll
    for (int q = 0; q < 2; ++q) {
        int g = blockIdx.x * 512 + q * 256 + tid;
        float mx = s[q][0];
#pragma unroll
        for (int i = 1; i < 8; ++i) mx = fmaxf(mx, s[q][i]);
        float sum = 0.f;
#pragma unroll
        for (int i = 0; i < 8; ++i) { s[q][i] = __expf(s[q][i] - mx); sum += s[q][i]; }
        float inv = 1.f / sum;
        f16x8 o8;
#pragma unroll
        for (int i = 0; i < 8; ++i) o8[i] = (f16)(s[q][i] * inv);
        *(f16x8*)(scores + (size_t)g * 8) = o8;
    }
}

// ---------------------------------------------------------------------------
// Kernel 2: main einsum, 32x32x16 f16 MFMA. Weights resident in LDS (64 KB =
// this block's o-tile half, fragment-ordered, staged ONCE, one barrier).
// Block = 512 thr (8 waves) x 64 pts/wave = 512 points, one o-tile (32 outs).
// Grid = 512 point-groups x 2 ot. ot = bx>>9 so both ot-blocks of the same
// points land on the same XCD (feat L2/L3 reuse).
// Per wave-iter: 2 ds_read_b128 + 4 feat dword + 4 MFMA. 16 waves/CU.
// ---------------------------------------------------------------------------
__global__ __launch_bounds__(512, 4) void k_main(
    const float* __restrict__ feat,
    const f16* __restrict__ scores,
    const f16* __restrict__ wbtA,
    const float* __restrict__ bn_g, const float* __restrict__ bn_b,
    float* __restrict__ out)
{
    __shared__ __align__(16) f16 lwb[32768];    // 64 KB

    const int tid  = threadIdx.x;
    const int lane = tid & 63;
    const int wave = tid >> 6;          // 0..7
    const int l31  = lane & 31;
    const int lh   = lane >> 5;         // 0..1

    const int ot = blockIdx.x >> 9;             // 0..1 (o-tile half)
    const int g  = blockIdx.x & 511;            // point-group
    const int pblock = g * 512;                 // global point base
    const int b    = pblock >> 15;
    const int pt0  = (pblock & 32767) + wave * 64;   // within-batch, 32-aligned
    const int pc0  = pt0 + l31;
    const int pc1  = pc0 + 32;

    // ---- stage this ot's 64 KB of fragment-ordered weights into LDS ----
    const f16* src = wbtA + ((size_t)ot << 15);      // 32768 f16
#pragma unroll
    for (int it = 0; it < 8; ++it) {
        int idx = it * 512 + tid;                    // 0..4095 16B-chunks
        *(int4*)&lwb[idx << 3] = *(const int4*)&src[idx << 3];
    }
    __syncthreads();

    const float* fb = feat + (size_t)b * 2097152;    // (64, 32768)

    const int gpt = pblock + wave * 64 + l31;
    f16x8 sv0 = *(const f16x8*)(scores + (size_t)gpt * 8);
    f16x8 sv1 = *(const f16x8*)(scores + (size_t)(gpt + 32) * 8);
    const f16x2 s0a = {sv0[0], sv0[1]}, s0b = {sv0[2], sv0[3]},
                s0c = {sv0[4], sv0[5]}, s0d = {sv0[6], sv0[7]};
    const f16x2 s1a = {sv1[0], sv1[1]}, s1b = {sv1[2], sv1[3]},
                s1c = {sv1[4], sv1[5]}, s1d = {sv1[6], sv1[7]};

    f32x16 acc0 = {}, acc1 = {};

    const f16* Alds = lwb + (lane << 3);             // lane's 16B slot

#pragma unroll 2
    for (int kk = 0; kk < 32; ++kk) {
        const float* fr = fb + ((size_t)(kk * 2 + lh) << 15);

        f16x8 aD = *(const f16x8*)(Alds + ((size_t)kk << 9));        // diff ks
        f16x8 aR = *(const f16x8*)(Alds + ((size_t)(kk + 32) << 9)); // raw ks

        float fv0 = fr[pc0], fv1 = fr[pc1];
        float fc0 = fr[pt0], fc1 = fr[pt0 + 32];

        f16 hR0 = (f16)fv0,          hR1 = (f16)fv1;
        f16 hD0 = (f16)(fv0 - fc0),  hD1 = (f16)(fv1 - fc1);
        f16x2 fR0 = {hR0, hR0}, fR1 = {hR1, hR1};
        f16x2 fD0 = {hD0, hD0}, fD1 = {hD1, hD1};

        f16x2 d0a = fD0 * s0a, d0b = fD0 * s0b, d0c = fD0 * s0c, d0d = fD0 * s0d;
        f16x2 d1a = fD1 * s1a, d1b = fD1 * s1b, d1c = fD1 * s1c, d1d = fD1 * s1d;
        f16x2 r0a = fR0 * s0a, r0b = fR0 * s0b, r0c = fR0 * s0c, r0d = fR0 * s0d;
        f16x2 r1a = fR1 * s1a, r1b = fR1 * s1b, r1c = fR1 * s1c, r1d = fR1 * s1d;

        f16x8 bD0 = {d0a[0],d0a[1],d0b[0],d0b[1],d0c[0],d0c[1],d0d[0],d0d[1]};
        f16x8 bD1 = {d1a[0],d1a[1],d1b[0],d1b[1],d1c[0],d1c[1],d1d[0],d1d[1]};
        f16x8 bR0 = {r0a[0],r0a[1],r0b[0],r0b[1],r0c[0],r0c[1],r0d[0],r0d[1]};
        f16x8 bR1 = {r1a[0],r1a[1],r1b[0],r1b[1],r1c[0],r1c[1],r1d[0],r1d[1]};

        acc0 = __builtin_amdgcn_mfma_f32_32x32x16_f16(aD, bD0, acc0, 0, 0, 0);
        acc1 = __builtin_amdgcn_mfma_f32_32x32x16_f16(aD, bD1, acc1, 0, 0, 0);
        acc0 = __builtin_amdgcn_mfma_f32_32x32x16_f16(aR, bR0, acc0, 0, 0, 0);
        acc1 = __builtin_amdgcn_mfma_f32_32x32x16_f16(aR, bR1, acc1, 0, 0, 0);
    }

    // ---------------- epilogue: BN + ReLU + coalesced store ------------------
    // C layout: col = lane&31, row = (r&3) + 8*(r>>2) + 4*lh
#pragma unroll
    for (int q = 0; q < 2; ++q) {
        int pcol = (q == 0) ? pc0 : pc1;
        const f32x16& a = (q == 0) ? acc0 : acc1;
#pragma unroll
        for (int r = 0; r < 16; ++r) {
            int o = ot * 32 + (r & 3) + ((r >> 2) << 3) + (lh << 2);
            float v = a[r];
            v = v * (bn_g[o] * BNSCL) + bn_b[o];
            v = fmaxf(v, 0.f);
            out[((size_t)(b * 64 + o) << 15) + pcol] = v;
        }
    }
}

// ---------------------------------------------------------------------------
extern "C" void kernel_launch(void* const* d_in, const int* in_sizes, int n_in,
                              void* d_out, int out_size, void* d_ws, size_t ws_size,
                              hipStream_t stream)
{
    const float* features = (const float*)d_in[0];
    const float* xyz      = (const float*)d_in[1];
    const float* w1  = (const float*)d_in[2];
    const float* g1  = (const float*)d_in[3];
    const float* be1 = (const float*)d_in[4];
    const float* w2  = (const float*)d_in[5];
    const float* g2  = (const float*)d_in[6];
    const float* be2 = (const float*)d_in[7];
    const float* w3  = (const float*)d_in[8];
    const float* g3  = (const float*)d_in[9];
    const float* be3 = (const float*)d_in[10];
    const float* w4  = (const float*)d_in[11];
    const float* b4  = (const float*)d_in[12];
    const float* wb  = (const float*)d_in[13];
    const float* bn_g = (const float*)d_in[14];
    const float* bn_b = (const float*)d_in[15];

    f16* scores = (f16*)d_ws;                             // 4 MB
    f16* wbtA   = (f16*)((char*)d_ws + (4u << 20));       // 128 KB

    k_scores<<<512, 256, 0, stream>>>(xyz, w1, g1, be1, w2, g2, be2,
                                      w3, g3, be3, w4, b4, wb, wbtA, scores);
    k_main<<<1024, 512, 0, stream>>>(features, scores, wbtA, bn_g, bn_b,
                                     (float*)d_out);
}